// Round 1
// 604.324 us; speedup vs baseline: 1.1259x; 1.1259x over previous
//
#include <hip/hip_runtime.h>

#define N_  128
#define IC_ 3
#define OC_ 16
#define H_  256
#define W_  256
#define OH_ 254
#define OW_ 254

typedef float v2f __attribute__((ext_vector_type(2)));

// Packed double-safe mish: mish(x) = x*(t-1)/(t+1), t = (1+e^x)^2.
// Overflow guard via min-clamp on t (packable) instead of divergent select:
// t=inf -> clamped to 1e30 -> (t-1)/(t+1) ~= 1 -> result = x. Exact enough for x>20.
__device__ __forceinline__ v2f mish2(v2f x) {
    v2f xe = x * 1.44269504088896340f;           // v_pk_mul
    v2f e;
    e.x = __builtin_amdgcn_exp2f(xe.x);          // trans
    e.y = __builtin_amdgcn_exp2f(xe.y);
    v2f p = e + 1.0f;                            // v_pk_add
    v2f t = p * p;                               // v_pk_mul
    v2f clampv = {1e30f, 1e30f};
    t = __builtin_elementwise_min(t, clampv);    // 2x v_min
    v2f num = (t - 1.0f) * x;                    // pk_add + pk_mul
    v2f den = t + 1.0f;                          // pk_add
    v2f r;
    r.x = __builtin_amdgcn_rcpf(den.x);          // trans
    r.y = __builtin_amdgcn_rcpf(den.y);
    return num * r;                              // pk_mul
}

// Repack weights [oc][ic][kh][kw] -> [r][oc] (r = ic*9+kh*3+kw) so that for a
// fixed tap r the 16 oc values are contiguous: uniform s_load_dwordx16 in the
// main kernel, oc-pairs land in even-aligned SGPR pairs feeding v_pk_fma_f32.
__global__ void repack_w(const float* __restrict__ w, float* __restrict__ pw) {
    int i = threadIdx.x;
    if (i < 432) {
        int oc = i / 27;
        int r  = i - oc * 27;
        pw[r * 16 + oc] = w[i];
    }
}

__global__ __launch_bounds__(256) void conv_mish_kernel(
    const float* __restrict__ x, const float* __restrict__ pw,
    const float* __restrict__ bias, float* __restrict__ out)
{
    int t    = threadIdx.x;
    int p    = t & 127;             // pair index along ow
    int row2 = t >> 7;              // which of the 2 rows this block covers
    int oh   = blockIdx.x * 2 + row2;
    int n    = blockIdx.y;
    if (p >= 127) return;           // 127 pairs cover ow 0..253
    int ow0  = p * 2;

    // acc[q] holds oc pair (2q, 2q+1); acc0 = col ow0, acc1 = col ow0+1
    v2f acc0[8], acc1[8];
    const v2f* bq = (const v2f*)bias;           // uniform -> s_load
    #pragma unroll
    for (int q = 0; q < 8; ++q) { v2f b = bq[q]; acc0[q] = b; acc1[q] = b; }

    const float* xb = x + (size_t)n * (IC_ * H_ * W_);
    const v2f*   wv = (const v2f*)pw;           // uniform indices -> s_load

    #pragma unroll 1
    for (int s = 0; s < 9; ++s) {
        int ic = s / 3;
        int kh = s - ic * 3;
        const float* rowp = xb + ic * (H_ * W_) + (oh + kh) * W_ + ow0;
        float2 a  = *(const float2*)(rowp);      // cols ow0..ow0+1 (8B aligned)
        float2 b2 = *(const float2*)(rowp + 2);  // cols ow0+2..ow0+3
        float in[4] = {a.x, a.y, b2.x, b2.y};
        #pragma unroll
        for (int kw = 0; kw < 3; ++kw) {
            v2f iv0 = {in[kw],     in[kw]};      // splat (op_sel / pk_mov)
            v2f iv1 = {in[kw + 1], in[kw + 1]};
            #pragma unroll
            for (int q = 0; q < 8; ++q) {
                v2f w2 = wv[s * 24 + kw * 8 + q];   // SGPR pair
                acc0[q] += w2 * iv0;                 // v_pk_fma_f32
                acc1[q] += w2 * iv1;
            }
        }
    }

    float* ob = out + (size_t)n * (OC_ * OH_ * OW_) + (size_t)oh * OW_ + ow0;
    #pragma unroll
    for (int q = 0; q < 8; ++q) {
        v2f v0 = mish2(mish2(acc0[q]));   // oc pair @ col ow0
        v2f v1 = mish2(mish2(acc1[q]));   // oc pair @ col ow0+1
        v2f s0 = {v0.x, v1.x};            // oc=2q:   (col ow0, ow0+1)
        v2f s1 = {v0.y, v1.y};            // oc=2q+1: (col ow0, ow0+1)
        __builtin_nontemporal_store(s0, (v2f*)(ob + (size_t)(2 * q)     * (OH_ * OW_)));
        __builtin_nontemporal_store(s1, (v2f*)(ob + (size_t)(2 * q + 1) * (OH_ * OW_)));
    }
}

extern "C" void kernel_launch(void* const* d_in, const int* in_sizes, int n_in,
                              void* d_out, int out_size, void* d_ws, size_t ws_size,
                              hipStream_t stream) {
    const float* x = (const float*)d_in[0];
    const float* w = (const float*)d_in[1];
    const float* b = (const float*)d_in[2];
    float* pw = (float*)d_ws;                       // 432 floats = 1728 B
    repack_w<<<dim3(1), dim3(512), 0, stream>>>(w, pw);
    dim3 grid(OH_ / 2, N_);   // (127, 128)
    dim3 block(256);
    conv_mish_kernel<<<grid, block, 0, stream>>>(x, pw, b, (float*)d_out);
}